// Round 5
// baseline (1545.766 us; speedup 1.0000x reference)
//
#include <hip/hip_runtime.h>
#include <hip/hip_fp16.h>

#define B_  2
#define S_  2048
#define NH  16
#define HD  64
#define DM  1024
#define SCAL 0.125f
#define BSN (B_*S_*NH)   // 65536, stride of one lpart slab

typedef _Float16 f16;
typedef _Float16 f16x4 __attribute__((ext_vector_type(4)));
typedef _Float16 f16x8 __attribute__((ext_vector_type(8)));
typedef float    f32x4 __attribute__((ext_vector_type(4)));

#define MFMA16(a,b,c) __builtin_amdgcn_mfma_f32_16x16x32_f16(a,b,c,0,0,0)

// ---------------------------------------------------------------------------
// GEMM: C[M=4096][N=1024] = X @ W^T + bias   (W row-major [out][in])
// MODE 0: q  -> perm fp16 [b][n][seq][64], scaled by SCAL
// MODE 1: k  -> perm fp16 [b][n][seq][64]
// MODE 2: v  -> transposed fp16 [b][n][64][seq]
// MODE 3: out-proj: X = 2 fp32 partials (summed), out fp32 [m][n]
// ---------------------------------------------------------------------------
template<int MODE>
__global__ __launch_bounds__(256) void gemm_k(const float* __restrict__ X,
    const float* __restrict__ W, const float* __restrict__ bias,
    void* __restrict__ outp, float scale)
{
    __shared__ __align__(16) f16 As[128][40];   // pad 32->40 halves (80B stride)
    __shared__ __align__(16) f16 Bs[128][40];
    const int tid = threadIdx.x;
    const int wave = tid >> 6, lane = tid & 63;
    const int wm = wave >> 1, wn = wave & 1;
    const int lr = lane & 15, lg = lane >> 4;
    const int m0 = blockIdx.x * 128, n0 = blockIdx.y * 128;

    f32x4 acc[4][4];
    #pragma unroll
    for (int s = 0; s < 4; s++)
        #pragma unroll
        for (int f = 0; f < 4; f++) acc[s][f] = (f32x4)(0.0f);

    const int srow = tid >> 3;          // 0..31
    const int sk4  = (tid & 7) * 4;     // 0..28

    for (int kt = 0; kt < DM; kt += 32) {
        __syncthreads();
        #pragma unroll
        for (int i = 0; i < 4; i++) {
            const int r = srow + i * 32;
            float4 va;
            const float* xp = X + (size_t)(m0 + r) * DM + kt + sk4;
            if (MODE == 3) {
                float4 p0 = *(const float4*)xp;
                float4 p1 = *(const float4*)(xp + 4194304);
                va.x = p0.x + p1.x;
                va.y = p0.y + p1.y;
                va.z = p0.z + p1.z;
                va.w = p0.w + p1.w;
            } else {
                va = *(const float4*)xp;
            }
            f16x4 ha = { (f16)va.x, (f16)va.y, (f16)va.z, (f16)va.w };
            *(f16x4*)&As[r][sk4] = ha;
            float4 vb = *(const float4*)(W + (size_t)(n0 + r) * DM + kt + sk4);
            f16x4 hb = { (f16)vb.x, (f16)vb.y, (f16)vb.z, (f16)vb.w };
            *(f16x4*)&Bs[r][sk4] = hb;
        }
        __syncthreads();
        f16x8 af[4], bf[4];
        #pragma unroll
        for (int s = 0; s < 4; s++) af[s] = *(const f16x8*)&As[wm*64 + s*16 + lr][lg*8];
        #pragma unroll
        for (int f = 0; f < 4; f++) bf[f] = *(const f16x8*)&Bs[wn*64 + f*16 + lr][lg*8];
        #pragma unroll
        for (int s = 0; s < 4; s++)
            #pragma unroll
            for (int f = 0; f < 4; f++)
                acc[s][f] = MFMA16(af[s], bf[f], acc[s][f]);
    }

    float bcol[4];
    #pragma unroll
    for (int f = 0; f < 4; f++) bcol[f] = bias[n0 + wn*64 + f*16 + lr];

    #pragma unroll
    for (int s = 0; s < 4; s++) {
        const int mg = m0 + wm*64 + s*16 + lg*4;   // + r
        #pragma unroll
        for (int f = 0; f < 4; f++) {
            const int nc = n0 + wn*64 + f*16 + lr;
            if (MODE == 3) {
                float* o = (float*)outp;
                #pragma unroll
                for (int r = 0; r < 4; r++)
                    o[(size_t)(mg + r) * DM + nc] = acc[s][f][r] + bcol[f];
            } else {
                const int b = mg >> 11, seq = mg & 2047;
                const int head = nc >> 6, h = nc & 63;
                f16* o = (f16*)outp;
                if (MODE == 2) {
                    f16x4 pk = { (f16)(acc[s][f][0] + bcol[f]), (f16)(acc[s][f][1] + bcol[f]),
                                 (f16)(acc[s][f][2] + bcol[f]), (f16)(acc[s][f][3] + bcol[f]) };
                    *(f16x4*)&o[((size_t)((b*NH + head)*HD + h)) * S_ + seq] = pk;
                } else {
                    #pragma unroll
                    for (int r = 0; r < 4; r++)
                        o[((size_t)(b*NH + head) * S_ + seq + r) * HD + h] =
                            (f16)((acc[s][f][r] + bcol[f]) * scale);
                }
            }
        }
    }
}

// ---------------------------------------------------------------------------
// Softmax denominators: lpart[kc][b][q][n] = sum over this k-chunk of exp(S)
// grid (qt=128, kchunk=4, b=2), 256 thr; wave -> 4 heads. Plain stores.
// ---------------------------------------------------------------------------
__global__ __launch_bounds__(256) void sums_k(const f16* __restrict__ qw,
    const f16* __restrict__ kw, const int* __restrict__ amask, float* __restrict__ lpart)
{
    const int tid = threadIdx.x, wave = tid >> 6, lane = tid & 63;
    const int lr = lane & 15, lg = lane >> 4;
    const int qt = blockIdx.x, kc = blockIdx.y, b = blockIdx.z;
    const int q0 = qt * 16, k0b = kc * 512;

    float rs[4][4];
    #pragma unroll
    for (int i = 0; i < 4; i++)
        #pragma unroll
        for (int r = 0; r < 4; r++) rs[i][r] = 0.f;

    f16x8 qf[4][2];
    #pragma unroll
    for (int hh = 0; hh < 4; hh++) {
        const int n = wave * 4 + hh;
        const f16* qp = qw + ((size_t)((b*NH + n) * S_) + q0 + lr) * HD + lg * 8;
        qf[hh][0] = *(const f16x8*)qp;
        qf[hh][1] = *(const f16x8*)(qp + 32);
    }
    #pragma unroll 2
    for (int kt = 0; kt < 8; kt++) {
        const int k0 = k0b + kt * 64;
        int km[4];
        #pragma unroll
        for (int ct = 0; ct < 4; ct++) km[ct] = amask[b * S_ + k0 + ct*16 + lr];
        #pragma unroll
        for (int hh = 0; hh < 4; hh++) {
            const int n = wave * 4 + hh;
            const f16* kp = kw + ((size_t)((b*NH + n) * S_) + k0) * HD;
            #pragma unroll
            for (int ct = 0; ct < 4; ct++) {
                f16x8 b0 = *(const f16x8*)(kp + (size_t)(ct*16 + lr) * HD + lg*8);
                f16x8 b1 = *(const f16x8*)(kp + (size_t)(ct*16 + lr) * HD + 32 + lg*8);
                f32x4 sv = (f32x4)(0.f);
                sv = MFMA16(qf[hh][0], b0, sv);
                sv = MFMA16(qf[hh][1], b1, sv);
                #pragma unroll
                for (int r = 0; r < 4; r++) rs[hh][r] += km[ct] ? 0.f : __expf(sv[r]);
            }
        }
    }
    #pragma unroll
    for (int hh = 0; hh < 4; hh++) {
        #pragma unroll
        for (int r = 0; r < 4; r++) {
            float v = rs[hh][r];
            v += __shfl_xor(v, 1);  v += __shfl_xor(v, 2);
            v += __shfl_xor(v, 4);  v += __shfl_xor(v, 8);
            if (lr == 0)
                lpart[(size_t)kc * BSN +
                      (size_t)(b*S_ + q0 + lg*4 + r) * NH + wave*4 + hh] = v;
        }
    }
}

// ---------------------------------------------------------------------------
// Attention. k-subtile 32, double-buffered P LDS [2][16n][16q][35], per tile:
//   writepass(t-1) from buf[(t-1)&1] (coalesced nt-stores, overlaps compute)
//   compute(t): QK -> exp -> P into buf[t&1], PV from own wave's P region
//   ONE raw s_barrier with lgkmcnt(0) only (global stores stay in flight)
// grid (qt=128, kq=2, b=2), 512 thr. Dyn LDS 2*16*16*35*4 = 71680 B.
// ---------------------------------------------------------------------------
#define PSTR 35
#define PBUF (16*16*PSTR)

__global__ __launch_bounds__(512, 4) void attn_k(const f16* __restrict__ qw,
    const f16* __restrict__ kw, const f16* __restrict__ vt,
    const int* __restrict__ amask, const float* __restrict__ lpart,
    float* __restrict__ attn, float* __restrict__ op)
{
    extern __shared__ float Ps[];
    const int tid = threadIdx.x, wave = tid >> 6, lane = tid & 63;
    const int lr = lane & 15, lg = lane >> 4;
    const int qt = blockIdx.x, kq = blockIdx.y, b = blockIdx.z;
    const int q0 = qt * 16;
    const int k0b = kq * 1024;
    const int wq = tid >> 5;      // writepass q row 0..15
    const int wk = tid & 31;      // writepass k col 0..31

    f16x8 qf[2][2];
    float rl[2][4];
    #pragma unroll
    for (int hh = 0; hh < 2; hh++) {
        const int n = wave * 2 + hh;
        const f16* qp = qw + ((size_t)((b*NH + n) * S_) + q0 + lr) * HD + lg * 8;
        qf[hh][0] = *(const f16x8*)qp;
        qf[hh][1] = *(const f16x8*)(qp + 32);
        #pragma unroll
        for (int r = 0; r < 4; r++) {
            const float* lp = lpart + (size_t)(b*S_ + q0 + lg*4 + r) * NH + n;
            rl[hh][r] = 1.0f / (lp[0] + lp[BSN] + lp[2*BSN] + lp[3*BSN]);
        }
    }
    f32x4 accO[2][4];
    #pragma unroll
    for (int i = 0; i < 2; i++)
        #pragma unroll
        for (int j = 0; j < 4; j++) accO[i][j] = (f32x4)(0.f);

    for (int t = 0; t < 32; t++) {
        const int k0 = k0b + t * 32;
        float* Pb = Ps + (t & 1) * PBUF;

        // ---- writepass of tile t-1 (reads other buffer; overlaps compute) ----
        if (t > 0) {
            const float* Pp = Ps + ((t - 1) & 1) * PBUF;
            float pv[16];
            #pragma unroll
            for (int n = 0; n < 16; n++)
                pv[n] = Pp[n * (16*PSTR) + wq * PSTR + wk];
            float* dst = attn + ((size_t)(b*S_ + q0 + wq) * S_ + (k0 - 32) + wk) * NH;
            #pragma unroll
            for (int j = 0; j < 4; j++) {
                f32x4 sv = { pv[j*4+0], pv[j*4+1], pv[j*4+2], pv[j*4+3] };
                __builtin_nontemporal_store(sv, (f32x4*)(dst + j*4));
            }
        }

        // ---- compute tile t ----
        int km[2];
        #pragma unroll
        for (int ct = 0; ct < 2; ct++) km[ct] = amask[b * S_ + k0 + ct*16 + lr];
        #pragma unroll
        for (int hh = 0; hh < 2; hh++) {
            const int n = wave * 2 + hh;
            const f16* kp = kw + ((size_t)((b*NH + n) * S_) + k0) * HD;
            f32x4 sfr[2];
            #pragma unroll
            for (int ct = 0; ct < 2; ct++) {
                f16x8 b0 = *(const f16x8*)(kp + (size_t)(ct*16 + lr) * HD + lg*8);
                f16x8 b1 = *(const f16x8*)(kp + (size_t)(ct*16 + lr) * HD + 32 + lg*8);
                f32x4 sv = (f32x4)(0.f);
                sv = MFMA16(qf[hh][0], b0, sv);
                sv = MFMA16(qf[hh][1], b1, sv);
                sfr[ct] = sv;
            }
            float* myP = Pb + n * (16*PSTR);
            #pragma unroll
            for (int ct = 0; ct < 2; ct++) {
                #pragma unroll
                for (int r = 0; r < 4; r++) {
                    float p = km[ct] ? 0.0f : __expf(sfr[ct][r]) * rl[hh][r];
                    myP[(lg*4 + r) * PSTR + ct*16 + lr] = p;
                }
            }
            // PV A-fragment from own wave's P (same-wave LDS dep, compiler-ordered)
            f32x4 pa0 = *(const f32x4*)&myP[lr * PSTR + lg*8];
            f32x4 pa1 = *(const f32x4*)&myP[lr * PSTR + lg*8 + 4];
            f16x8 a0 = { (f16)pa0[0], (f16)pa0[1], (f16)pa0[2], (f16)pa0[3],
                         (f16)pa1[0], (f16)pa1[1], (f16)pa1[2], (f16)pa1[3] };
            #pragma unroll
            for (int hb = 0; hb < 4; hb++) {
                const f16* vp = vt + ((size_t)((b*NH + n) * HD) + hb*16 + lr) * S_ + k0;
                f16x8 v0 = *(const f16x8*)(vp + lg*8);
                accO[hh][hb] = MFMA16(a0, v0, accO[hh][hb]);
            }
        }

        // ---- barrier: order LDS only; leave global stores in flight ----
        __builtin_amdgcn_sched_barrier(0);
        asm volatile("s_waitcnt lgkmcnt(0)" ::: "memory");
        __builtin_amdgcn_s_barrier();
        __builtin_amdgcn_sched_barrier(0);
    }

    // ---- final writepass for tile 31 (buf 1) ----
    {
        const float* Pp = Ps + PBUF;
        const int k0 = k0b + 31 * 32;
        float pv[16];
        #pragma unroll
        for (int n = 0; n < 16; n++)
            pv[n] = Pp[n * (16*PSTR) + wq * PSTR + wk];
        float* dst = attn + ((size_t)(b*S_ + q0 + wq) * S_ + k0 + wk) * NH;
        #pragma unroll
        for (int j = 0; j < 4; j++) {
            f32x4 sv = { pv[j*4+0], pv[j*4+1], pv[j*4+2], pv[j*4+3] };
            __builtin_nontemporal_store(sv, (f32x4*)(dst + j*4));
        }
    }

    float* opk = op + (size_t)kq * 4194304;
    #pragma unroll
    for (int hh = 0; hh < 2; hh++) {
        const int n = wave * 2 + hh;
        #pragma unroll
        for (int hb = 0; hb < 4; hb++)
            #pragma unroll
            for (int r = 0; r < 4; r++)
                opk[(size_t)(b*S_ + q0 + lg*4 + r) * DM + n*HD + hb*16 + lr] = accO[hh][hb][r];
    }
}

// ---------------------------------------------------------------------------
extern "C" void kernel_launch(void* const* d_in, const int* in_sizes, int n_in,
                              void* d_out, int out_size, void* d_ws, size_t ws_size,
                              hipStream_t stream)
{
    const float* query = (const float*)d_in[0];
    const float* key   = (const float*)d_in[1];
    const float* value = (const float*)d_in[2];
    const int*   amask = (const int*)d_in[3];
    const float* Wq = (const float*)d_in[4];
    const float* bq = (const float*)d_in[5];
    const float* Wk = (const float*)d_in[6];
    const float* bk = (const float*)d_in[7];
    const float* Wv = (const float*)d_in[8];
    const float* bv = (const float*)d_in[9];
    const float* Wo = (const float*)d_in[10];
    const float* bo = (const float*)d_in[11];

    char* ws = (char*)d_ws;
    f16*   qw = (f16*)(ws + 0);            //  8 MB
    f16*   kw = (f16*)(ws + 8388608);      //  8 MB
    f16*   vt = (f16*)(ws + 16777216);     //  8 MB
    float* lp = (float*)(ws + 25165824);   //  1 MB (4 partial-sum slabs)
    float* op = (float*)(ws + 26214400);   // 32 MB (2 k-half partials)

    float* out0 = (float*)d_out;
    float* attn = out0 + 4194304;

    dim3 blk(256);
    dim3 g1(32, 8);
    gemm_k<0><<<g1, blk, 0, stream>>>(query, Wq, bq, (void*)qw, SCAL);
    gemm_k<1><<<g1, blk, 0, stream>>>(key,   Wk, bk, (void*)kw, 1.0f);
    gemm_k<2><<<g1, blk, 0, stream>>>(value, Wv, bv, (void*)vt, 1.0f);
    sums_k<<<dim3(128, 4, 2), blk, 0, stream>>>(qw, kw, amask, lp);
    attn_k<<<dim3(128, 2, 2), dim3(512), 71680, stream>>>(qw, kw, vt, amask, lp, attn, op);
    gemm_k<3><<<g1, blk, 0, stream>>>(op, Wo, bo, d_out, 1.0f);
}

// Round 7
// 1179.100 us; speedup vs baseline: 1.3110x; 1.3110x over previous
//
#include <hip/hip_runtime.h>
#include <hip/hip_fp16.h>

#define B_  2
#define S_  2048
#define NH  16
#define HD  64
#define DM  1024
#define SCAL 0.125f
#define BSN (B_*S_*NH)   // 65536, stride of one lpart slab

typedef _Float16 f16;
typedef _Float16 f16x4 __attribute__((ext_vector_type(4)));
typedef _Float16 f16x8 __attribute__((ext_vector_type(8)));
typedef float    f32x4 __attribute__((ext_vector_type(4)));

#define MFMA16(a,b,c) __builtin_amdgcn_mfma_f32_16x16x32_f16(a,b,c,0,0,0)

// ---------------------------------------------------------------------------
// GEMM: C[M=4096][N=1024] = X @ W^T + bias   (W row-major [out][in])
// MODE 0: q  -> perm fp16 [b][n][seq][64], scaled by SCAL
// MODE 1: k  -> perm fp16 [b][n][seq][64]
// MODE 2: v  -> transposed fp16 [b][n][64][seq]
// MODE 3: out-proj: X = 2 fp32 partials (summed), out fp32 [m][n]
// ---------------------------------------------------------------------------
template<int MODE>
__global__ __launch_bounds__(256) void gemm_k(const float* __restrict__ X,
    const float* __restrict__ W, const float* __restrict__ bias,
    void* __restrict__ outp, float scale)
{
    __shared__ __align__(16) f16 As[128][40];   // pad 32->40 halves (80B stride)
    __shared__ __align__(16) f16 Bs[128][40];
    const int tid = threadIdx.x;
    const int wave = tid >> 6, lane = tid & 63;
    const int wm = wave >> 1, wn = wave & 1;
    const int lr = lane & 15, lg = lane >> 4;
    const int m0 = blockIdx.x * 128, n0 = blockIdx.y * 128;

    f32x4 acc[4][4];
    #pragma unroll
    for (int s = 0; s < 4; s++)
        #pragma unroll
        for (int f = 0; f < 4; f++) acc[s][f] = (f32x4)(0.0f);

    const int srow = tid >> 3;          // 0..31
    const int sk4  = (tid & 7) * 4;     // 0..28

    for (int kt = 0; kt < DM; kt += 32) {
        __syncthreads();
        #pragma unroll
        for (int i = 0; i < 4; i++) {
            const int r = srow + i * 32;
            float4 va;
            const float* xp = X + (size_t)(m0 + r) * DM + kt + sk4;
            if (MODE == 3) {
                float4 p0 = *(const float4*)xp;
                float4 p1 = *(const float4*)(xp + 4194304);
                va.x = p0.x + p1.x;
                va.y = p0.y + p1.y;
                va.z = p0.z + p1.z;
                va.w = p0.w + p1.w;
            } else {
                va = *(const float4*)xp;
            }
            f16x4 ha = { (f16)va.x, (f16)va.y, (f16)va.z, (f16)va.w };
            *(f16x4*)&As[r][sk4] = ha;
            float4 vb = *(const float4*)(W + (size_t)(n0 + r) * DM + kt + sk4);
            f16x4 hb = { (f16)vb.x, (f16)vb.y, (f16)vb.z, (f16)vb.w };
            *(f16x4*)&Bs[r][sk4] = hb;
        }
        __syncthreads();
        f16x8 af[4], bf[4];
        #pragma unroll
        for (int s = 0; s < 4; s++) af[s] = *(const f16x8*)&As[wm*64 + s*16 + lr][lg*8];
        #pragma unroll
        for (int f = 0; f < 4; f++) bf[f] = *(const f16x8*)&Bs[wn*64 + f*16 + lr][lg*8];
        #pragma unroll
        for (int s = 0; s < 4; s++)
            #pragma unroll
            for (int f = 0; f < 4; f++)
                acc[s][f] = MFMA16(af[s], bf[f], acc[s][f]);
    }

    float bcol[4];
    #pragma unroll
    for (int f = 0; f < 4; f++) bcol[f] = bias[n0 + wn*64 + f*16 + lr];

    #pragma unroll
    for (int s = 0; s < 4; s++) {
        const int mg = m0 + wm*64 + s*16 + lg*4;   // + r
        #pragma unroll
        for (int f = 0; f < 4; f++) {
            const int nc = n0 + wn*64 + f*16 + lr;
            if (MODE == 3) {
                float* o = (float*)outp;
                #pragma unroll
                for (int r = 0; r < 4; r++)
                    o[(size_t)(mg + r) * DM + nc] = acc[s][f][r] + bcol[f];
            } else {
                const int b = mg >> 11, seq = mg & 2047;
                const int head = nc >> 6, h = nc & 63;
                f16* o = (f16*)outp;
                if (MODE == 2) {
                    f16x4 pk = { (f16)(acc[s][f][0] + bcol[f]), (f16)(acc[s][f][1] + bcol[f]),
                                 (f16)(acc[s][f][2] + bcol[f]), (f16)(acc[s][f][3] + bcol[f]) };
                    *(f16x4*)&o[((size_t)((b*NH + head)*HD + h)) * S_ + seq] = pk;
                } else {
                    #pragma unroll
                    for (int r = 0; r < 4; r++)
                        o[((size_t)(b*NH + head) * S_ + seq + r) * HD + h] =
                            (f16)((acc[s][f][r] + bcol[f]) * scale);
                }
            }
        }
    }
}

// ---------------------------------------------------------------------------
// Softmax denominators: lpart[kc][b][q][n] = sum over this k-chunk of exp(S)
// grid (qt=128, kchunk=4, b=2), 256 thr; wave -> 4 heads. Plain stores.
// ---------------------------------------------------------------------------
__global__ __launch_bounds__(256) void sums_k(const f16* __restrict__ qw,
    const f16* __restrict__ kw, const int* __restrict__ amask, float* __restrict__ lpart)
{
    const int tid = threadIdx.x, wave = tid >> 6, lane = tid & 63;
    const int lr = lane & 15, lg = lane >> 4;
    const int qt = blockIdx.x, kc = blockIdx.y, b = blockIdx.z;
    const int q0 = qt * 16, k0b = kc * 512;

    float rs[4][4];
    #pragma unroll
    for (int i = 0; i < 4; i++)
        #pragma unroll
        for (int r = 0; r < 4; r++) rs[i][r] = 0.f;

    f16x8 qf[4][2];
    #pragma unroll
    for (int hh = 0; hh < 4; hh++) {
        const int n = wave * 4 + hh;
        const f16* qp = qw + ((size_t)((b*NH + n) * S_) + q0 + lr) * HD + lg * 8;
        qf[hh][0] = *(const f16x8*)qp;
        qf[hh][1] = *(const f16x8*)(qp + 32);
    }
    #pragma unroll 2
    for (int kt = 0; kt < 8; kt++) {
        const int k0 = k0b + kt * 64;
        int km[4];
        #pragma unroll
        for (int ct = 0; ct < 4; ct++) km[ct] = amask[b * S_ + k0 + ct*16 + lr];
        #pragma unroll
        for (int hh = 0; hh < 4; hh++) {
            const int n = wave * 4 + hh;
            const f16* kp = kw + ((size_t)((b*NH + n) * S_) + k0) * HD;
            #pragma unroll
            for (int ct = 0; ct < 4; ct++) {
                f16x8 b0 = *(const f16x8*)(kp + (size_t)(ct*16 + lr) * HD + lg*8);
                f16x8 b1 = *(const f16x8*)(kp + (size_t)(ct*16 + lr) * HD + 32 + lg*8);
                f32x4 sv = (f32x4)(0.f);
                sv = MFMA16(qf[hh][0], b0, sv);
                sv = MFMA16(qf[hh][1], b1, sv);
                #pragma unroll
                for (int r = 0; r < 4; r++) rs[hh][r] += km[ct] ? 0.f : __expf(sv[r]);
            }
        }
    }
    #pragma unroll
    for (int hh = 0; hh < 4; hh++) {
        #pragma unroll
        for (int r = 0; r < 4; r++) {
            float v = rs[hh][r];
            v += __shfl_xor(v, 1);  v += __shfl_xor(v, 2);
            v += __shfl_xor(v, 4);  v += __shfl_xor(v, 8);
            if (lr == 0)
                lpart[(size_t)kc * BSN +
                      (size_t)(b*S_ + q0 + lg*4 + r) * NH + wave*4 + hh] = v;
        }
    }
}

// ---------------------------------------------------------------------------
// Attention. k-subtile 32, double-buffered P LDS [2][16n][16q][35], per tile:
//   writepass(t-1) from buf[(t-1)&1] (coalesced CACHED stores -> merge in L2)
//   compute(t): QK -> exp -> P into buf[t&1], PV from own wave's P region
//   ONE raw s_barrier with lgkmcnt(0) only (global stores stay in flight)
// grid (qt=128, kq=2, b=2), 512 thr. Dyn LDS 2*16*16*35*4 = 71680 B.
// ---------------------------------------------------------------------------
#define PSTR 35
#define PBUF (16*16*PSTR)

__global__ __launch_bounds__(512, 4) void attn_k(const f16* __restrict__ qw,
    const f16* __restrict__ kw, const f16* __restrict__ vt,
    const int* __restrict__ amask, const float* __restrict__ lpart,
    float* __restrict__ attn, float* __restrict__ op)
{
    extern __shared__ float Ps[];
    const int tid = threadIdx.x, wave = tid >> 6, lane = tid & 63;
    const int lr = lane & 15, lg = lane >> 4;
    const int qt = blockIdx.x, kq = blockIdx.y, b = blockIdx.z;
    const int q0 = qt * 16;
    const int k0b = kq * 1024;
    const int wq = tid >> 5;      // writepass q row 0..15
    const int wk = tid & 31;      // writepass k col 0..31

    f16x8 qf[2][2];
    float rl[2][4];
    #pragma unroll
    for (int hh = 0; hh < 2; hh++) {
        const int n = wave * 2 + hh;
        const f16* qp = qw + ((size_t)((b*NH + n) * S_) + q0 + lr) * HD + lg * 8;
        qf[hh][0] = *(const f16x8*)qp;
        qf[hh][1] = *(const f16x8*)(qp + 32);
        #pragma unroll
        for (int r = 0; r < 4; r++) {
            const float* lp = lpart + (size_t)(b*S_ + q0 + lg*4 + r) * NH + n;
            rl[hh][r] = 1.0f / (lp[0] + lp[BSN] + lp[2*BSN] + lp[3*BSN]);
        }
    }
    f32x4 accO[2][4];
    #pragma unroll
    for (int i = 0; i < 2; i++)
        #pragma unroll
        for (int j = 0; j < 4; j++) accO[i][j] = (f32x4)(0.f);

    for (int t = 0; t < 32; t++) {
        const int k0 = k0b + t * 32;
        float* Pb = Ps + (t & 1) * PBUF;

        // ---- writepass of tile t-1 (reads other buffer; overlaps compute) ----
        if (t > 0) {
            const float* Pp = Ps + ((t - 1) & 1) * PBUF;
            float pv[16];
            #pragma unroll
            for (int n = 0; n < 16; n++)
                pv[n] = Pp[n * (16*PSTR) + wq * PSTR + wk];
            float* dst = attn + ((size_t)(b*S_ + q0 + wq) * S_ + (k0 - 32) + wk) * NH;
            #pragma unroll
            for (int j = 0; j < 4; j++) {
                f32x4 sv = { pv[j*4+0], pv[j*4+1], pv[j*4+2], pv[j*4+3] };
                *(f32x4*)(dst + j*4) = sv;   // cached store: merges in L2
            }
        }

        // ---- compute tile t ----
        int km[2];
        #pragma unroll
        for (int ct = 0; ct < 2; ct++) km[ct] = amask[b * S_ + k0 + ct*16 + lr];
        #pragma unroll
        for (int hh = 0; hh < 2; hh++) {
            const int n = wave * 2 + hh;
            const f16* kp = kw + ((size_t)((b*NH + n) * S_) + k0) * HD;
            f32x4 sfr[2];
            #pragma unroll
            for (int ct = 0; ct < 2; ct++) {
                f16x8 b0 = *(const f16x8*)(kp + (size_t)(ct*16 + lr) * HD + lg*8);
                f16x8 b1 = *(const f16x8*)(kp + (size_t)(ct*16 + lr) * HD + 32 + lg*8);
                f32x4 sv = (f32x4)(0.f);
                sv = MFMA16(qf[hh][0], b0, sv);
                sv = MFMA16(qf[hh][1], b1, sv);
                sfr[ct] = sv;
            }
            float* myP = Pb + n * (16*PSTR);
            #pragma unroll
            for (int ct = 0; ct < 2; ct++) {
                #pragma unroll
                for (int r = 0; r < 4; r++) {
                    float p = km[ct] ? 0.0f : __expf(sfr[ct][r]) * rl[hh][r];
                    myP[(lg*4 + r) * PSTR + ct*16 + lr] = p;
                }
            }
            // PV A-fragment from own wave's P (same-wave LDS dep, compiler-ordered)
            f32x4 pa0 = *(const f32x4*)&myP[lr * PSTR + lg*8];
            f32x4 pa1 = *(const f32x4*)&myP[lr * PSTR + lg*8 + 4];
            f16x8 a0 = { (f16)pa0[0], (f16)pa0[1], (f16)pa0[2], (f16)pa0[3],
                         (f16)pa1[0], (f16)pa1[1], (f16)pa1[2], (f16)pa1[3] };
            #pragma unroll
            for (int hb = 0; hb < 4; hb++) {
                const f16* vp = vt + ((size_t)((b*NH + n) * HD) + hb*16 + lr) * S_ + k0;
                f16x8 v0 = *(const f16x8*)(vp + lg*8);
                accO[hh][hb] = MFMA16(a0, v0, accO[hh][hb]);
            }
        }

        // ---- barrier: order LDS only; leave global stores in flight ----
        __builtin_amdgcn_sched_barrier(0);
        asm volatile("s_waitcnt lgkmcnt(0)" ::: "memory");
        __builtin_amdgcn_s_barrier();
        __builtin_amdgcn_sched_barrier(0);
    }

    // ---- final writepass for tile 31 (buf 1) ----
    {
        const float* Pp = Ps + PBUF;
        const int k0 = k0b + 31 * 32;
        float pv[16];
        #pragma unroll
        for (int n = 0; n < 16; n++)
            pv[n] = Pp[n * (16*PSTR) + wq * PSTR + wk];
        float* dst = attn + ((size_t)(b*S_ + q0 + wq) * S_ + k0 + wk) * NH;
        #pragma unroll
        for (int j = 0; j < 4; j++) {
            f32x4 sv = { pv[j*4+0], pv[j*4+1], pv[j*4+2], pv[j*4+3] };
            *(f32x4*)(dst + j*4) = sv;
        }
    }

    float* opk = op + (size_t)kq * 4194304;
    #pragma unroll
    for (int hh = 0; hh < 2; hh++) {
        const int n = wave * 2 + hh;
        #pragma unroll
        for (int hb = 0; hb < 4; hb++)
            #pragma unroll
            for (int r = 0; r < 4; r++)
                opk[(size_t)(b*S_ + q0 + lg*4 + r) * DM + n*HD + hb*16 + lr] = accO[hh][hb][r];
    }
}

// ---------------------------------------------------------------------------
extern "C" void kernel_launch(void* const* d_in, const int* in_sizes, int n_in,
                              void* d_out, int out_size, void* d_ws, size_t ws_size,
                              hipStream_t stream)
{
    const float* query = (const float*)d_in[0];
    const float* key   = (const float*)d_in[1];
    const float* value = (const float*)d_in[2];
    const int*   amask = (const int*)d_in[3];
    const float* Wq = (const float*)d_in[4];
    const float* bq = (const float*)d_in[5];
    const float* Wk = (const float*)d_in[6];
    const float* bk = (const float*)d_in[7];
    const float* Wv = (const float*)d_in[8];
    const float* bv = (const float*)d_in[9];
    const float* Wo = (const float*)d_in[10];
    const float* bo = (const float*)d_in[11];

    char* ws = (char*)d_ws;
    f16*   qw = (f16*)(ws + 0);            //  8 MB
    f16*   kw = (f16*)(ws + 8388608);      //  8 MB
    f16*   vt = (f16*)(ws + 16777216);     //  8 MB
    float* lp = (float*)(ws + 25165824);   //  1 MB (4 partial-sum slabs)
    float* op = (float*)(ws + 26214400);   // 32 MB (2 k-half partials)

    float* out0 = (float*)d_out;
    float* attn = out0 + 4194304;

    dim3 blk(256);
    dim3 g1(32, 8);
    gemm_k<0><<<g1, blk, 0, stream>>>(query, Wq, bq, (void*)qw, SCAL);
    gemm_k<1><<<g1, blk, 0, stream>>>(key,   Wk, bk, (void*)kw, 1.0f);
    gemm_k<2><<<g1, blk, 0, stream>>>(value, Wv, bv, (void*)vt, 1.0f);
    sums_k<<<dim3(128, 4, 2), blk, 0, stream>>>(qw, kw, amask, lp);
    attn_k<<<dim3(128, 2, 2), dim3(512), 71680, stream>>>(qw, kw, vt, amask, lp, attn, op);
    gemm_k<3><<<g1, blk, 0, stream>>>(op, Wo, bo, d_out, 1.0f);
}